// Round 1
// baseline (77.517 us; speedup 1.0000x reference)
//
#include <hip/hip_runtime.h>
#include <hip/hip_bf16.h>

#define B_ 8192
#define T_ 128
#define I_ 28
#define H_ 64
#define O_ 10

#define XS 20   // u32 stride per batch-row in x ring (= 40 bf16, 16B-aligned rows)
#define HS 72   // ushort stride per batch-row in h buffer (144 B, 16B-aligned)
#define RING 5
#define PF 4

typedef __attribute__((ext_vector_type(8))) short bf16x8;
typedef __attribute__((ext_vector_type(4))) float f32x4;

__device__ __forceinline__ unsigned short f2bf(float f) {
    unsigned int u = __builtin_bit_cast(unsigned int, f);
    u += 0x7fffu + ((u >> 16) & 1u);   // RNE
    return (unsigned short)(u >> 16);
}
__device__ __forceinline__ float bf2f(unsigned short h) {
    unsigned int u = ((unsigned int)h) << 16;
    return __builtin_bit_cast(float, u);
}
__device__ __forceinline__ float fast_tanh(float x) {
    float ax = fabsf(x);
    float t = __expf(-2.0f * ax);                       // e^{-2|x|}, v_exp path
    float r = (1.0f - t) * __builtin_amdgcn_rcpf(1.0f + t);
    return copysignf(r, x);
}

__launch_bounds__(256, 2)
__global__ void rnn_fused_kernel(const float* __restrict__ x,
                                 const float* __restrict__ W_ih,
                                 const float* __restrict__ W_hh,
                                 const float* __restrict__ b_ih,
                                 const float* __restrict__ b_hh,
                                 const float* __restrict__ W_out,
                                 const float* __restrict__ b_out,
                                 float* __restrict__ out) {
    __shared__ __align__(16) unsigned int x_ring[RING][16 * XS];
    __shared__ __align__(16) unsigned short h_lds[2][16 * HS];

    const int tid = threadIdx.x;
    const int lane = tid & 63;
    const int nt = tid >> 6;          // wave id == N-tile (h columns nt*16..+15)
    const int b0 = blockIdx.x * 16;   // batch tile base

    // zero-init LDS (h0 = 0; x ring pad columns k=28..39 stay 0 forever)
    {
        unsigned int* xr = &x_ring[0][0];
        for (int i = tid; i < RING * 16 * XS; i += 256) xr[i] = 0u;
        unsigned short* hp = &h_lds[0][0];
        for (int i = tid; i < 2 * 16 * HS; i += 256) hp[i] = 0;
    }

    // ---- per-wave constant fragments (B operands), loaded once ----
    const int l15 = lane & 15;
    const int kb4 = lane >> 4;
    const int n = nt * 16 + l15;      // output h column this lane owns
    bf16x8 wih, whh0, whh1;
#pragma unroll
    for (int j = 0; j < 8; ++j) {
        int k = kb4 * 8 + j;
        // B[k][n] = W^T[k][n] = W[n][k]
        wih[j]  = (k < I_) ? (short)f2bf(W_ih[n * I_ + k]) : (short)0;
        whh0[j] = (short)f2bf(W_hh[n * H_ + k]);
        whh1[j] = (short)f2bf(W_hh[n * H_ + 32 + k]);
    }
    const float bias = b_ih[n] + b_hh[n];

    // staging assignment: 224 threads each move one float2 (2 of the 28 inputs)
    const int sb = tid / 14;          // batch row 0..15
    const int si = tid % 14;          // float2 index within row
    const bool stager = (tid < 224);
    const size_t xrow = (size_t)(b0 + sb) * (T_ * I_) + 2 * si;

    // prologue: stage t = 0..PF-1 into slots 0..PF-1
    for (int tp = 0; tp < PF; ++tp) {
        if (stager) {
            const float2 xv = *reinterpret_cast<const float2*>(x + xrow + tp * I_);
            x_ring[tp][sb * XS + si] =
                ((unsigned int)f2bf(xv.y) << 16) | (unsigned int)f2bf(xv.x);
        }
    }
    __syncthreads();

    for (int t = 0; t < T_; ++t) {
        const int cur = t & 1;
        const int slot = t % RING;

        // issue next prefetch load early (independent of recurrence)
        float2 xv;
        const bool do_stage = stager && (t + PF < T_);
        if (do_stage) {
            xv = *reinterpret_cast<const float2*>(x + xrow + (t + PF) * I_);
        }

        // A fragments: row = lane&15, k = (lane>>4)*8 + j  (8 contiguous bf16)
        bf16x8 axf = *reinterpret_cast<const bf16x8*>(&x_ring[slot][l15 * XS + kb4 * 4]);
        bf16x8 ah0 = *reinterpret_cast<const bf16x8*>(&h_lds[cur][l15 * HS + kb4 * 8]);
        bf16x8 ah1 = *reinterpret_cast<const bf16x8*>(&h_lds[cur][l15 * HS + 32 + kb4 * 8]);

        f32x4 acc = {bias, bias, bias, bias};
        acc = __builtin_amdgcn_mfma_f32_16x16x32_bf16(axf, wih, acc, 0, 0, 0);
        acc = __builtin_amdgcn_mfma_f32_16x16x32_bf16(ah0, whh0, acc, 0, 0, 0);
        acc = __builtin_amdgcn_mfma_f32_16x16x32_bf16(ah1, whh1, acc, 0, 0, 0);

        // land the prefetched tile in its ring slot (distinct from slot being read)
        if (do_stage) {
            x_ring[(t + PF) % RING][sb * XS + si] =
                ((unsigned int)f2bf(xv.y) << 16) | (unsigned int)f2bf(xv.x);
        }

        // tanh + write h into the other buffer
        const int nxt = cur ^ 1;
#pragma unroll
        for (int r = 0; r < 4; ++r) {
            const int m = kb4 * 4 + r;            // batch row (C layout: row=(l>>4)*4+r)
            h_lds[nxt][m * HS + n] = f2bf(fast_tanh(acc[r]));
        }
        __syncthreads();
    }

    // epilogue: out[b][o] = h_last . W_out[o] + b_out[o]; final h is in buffer 0
    if (tid < 160) {
        const int bl = tid & 15;
        const int o = tid >> 4;
        float s = b_out[o];
        const unsigned short* hrow = &h_lds[0][bl * HS];
#pragma unroll
        for (int k = 0; k < H_; ++k)
            s += bf2f(hrow[k]) * W_out[o * H_ + k];
        out[(size_t)(b0 + bl) * O_ + o] = s;
    }
}

extern "C" void kernel_launch(void* const* d_in, const int* in_sizes, int n_in,
                              void* d_out, int out_size, void* d_ws, size_t ws_size,
                              hipStream_t stream) {
    const float* x     = (const float*)d_in[0];
    const float* W_ih  = (const float*)d_in[1];
    const float* W_hh  = (const float*)d_in[2];
    const float* b_ih  = (const float*)d_in[3];
    const float* b_hh  = (const float*)d_in[4];
    const float* W_out = (const float*)d_in[5];
    const float* b_out = (const float*)d_in[6];
    float* out = (float*)d_out;

    dim3 grid(B_ / 16);
    dim3 block(256);
    rnn_fused_kernel<<<grid, block, 0, stream>>>(x, W_ih, W_hh, b_ih, b_hh,
                                                 W_out, b_out, out);
}